// Round 3
// baseline (186.290 us; speedup 1.0000x reference)
//
#include <hip/hip_runtime.h>
#include <hip/hip_bf16.h>
#include <hip/hip_fp16.h>

#define N_NODES 50000
#define N_EDGES 640000

typedef __attribute__((ext_vector_type(8))) short bf16x8;
typedef __attribute__((ext_vector_type(4))) float f32x4;

static __device__ __forceinline__ short f2bf(float f) {
    __hip_bfloat16 h = __float2bfloat16(f);
    return *reinterpret_cast<const short*>(&h);
}

// MODE 0: f32 atomicAdd directly into out (fallback).
// MODE 1: packed f16 atomics into accum (d_ws), convert kernel finishes.
template<int MODE>
__global__ __launch_bounds__(256)
void edge_hyper_kernel(const float* __restrict__ x,
                       const int* __restrict__ ei,      // int32 [2][E]
                       const float* __restrict__ ev,
                       const float* __restrict__ nrm,
                       const float* __restrict__ W1,
                       const float* __restrict__ b1,
                       const float* __restrict__ W2,
                       const float* __restrict__ b2,
                       float* __restrict__ out,
                       __half* __restrict__ accum,
                       int ngroups)
{
    __shared__ float h_lds[4][17][16];

    const int tid  = threadIdx.x;
    const int wv   = tid >> 6;       // wave in block
    const int l    = tid & 63;       // lane
    const int r    = l & 15;         // A-row edge index in group / output col o
    const int half = l >> 4;         // 0..3

    // ---- B fragments: 17 c-tiles (c=0..15 from W2, c=16 = bias b2) ----
    // Tile c holds B[k=i, n=o] = W2[c, o*32 + i]; lane l: n = l&15,
    // k = (l>>4)*8 + j -> 8 consecutive floats. Same assumed k-map for A
    // and B, so any true k-permutation cancels in the K-sum.
    bf16x8 bfrag[17];
    {
        const int koff = half * 8;
        #pragma unroll
        for (int c = 0; c < 16; ++c) {
            const float* p = W2 + c * 512 + r * 32 + koff;
            bf16x8 t;
            #pragma unroll
            for (int j = 0; j < 8; ++j) t[j] = f2bf(p[j]);
            bfrag[c] = t;
        }
        const float* p = b2 + r * 32 + koff;
        bf16x8 t;
        #pragma unroll
        for (int j = 0; j < 8; ++j) t[j] = f2bf(p[j]);
        bfrag[16] = t;
    }

    // ---- per-lane hypernetwork constants: lane computes h[c] for
    // c = half*4+q, q=0..3, for edge e0+r ----
    float w1v0[4], w1v1[4], w1v2[4], b1v[4];
    #pragma unroll
    for (int q = 0; q < 4; ++q) {
        const int c = half * 4 + q;
        w1v0[q] = W1[c];
        w1v1[q] = W1[16 + c];
        w1v2[q] = W1[32 + c];
        b1v[q]  = b1[c];
    }

    // bias row of the h-contraction is constant 1.0 (folds b2 tile in)
    if (half == 0) h_lds[wv][16][r] = 1.0f;

    const int gw = blockIdx.x * 4 + wv;
    const int nw = gridDim.x * 4;

    for (int g = gw; g < ngroups; g += nw) {
        const int e0 = g * 16;
        const int eg = e0 + r;

        // ---- gather xe = concat(x[src], x[dst]); lane covers its own
        // A-fragment k-range i = half*8 .. half*8+7 ----
        const int idx = ei[(half >= 2 ? N_EDGES : 0) + eg];
        const float4* xr = reinterpret_cast<const float4*>(
            x + (size_t)idx * 16 + (half & 1) * 8);
        const float4 xa = xr[0];
        const float4 xb = xr[1];

        // ---- hypernetwork h = relu(ev@W1 + b1), exact f32 ----
        const float v0 = ev[eg * 3 + 0];
        const float v1 = ev[eg * 3 + 1];
        const float v2 = ev[eg * 3 + 2];
        // drain previous group's h reads before overwrite (wave-private region)
        asm volatile("s_waitcnt lgkmcnt(0)" ::: "memory");
        #pragma unroll
        for (int q = 0; q < 4; ++q) {
            float hv = b1v[q] + v0 * w1v0[q] + v1 * w1v1[q] + v2 * w1v2[q];
            h_lds[wv][half * 4 + q][r] = fmaxf(hv, 0.0f);
        }

        // ---- A fragment (xe in bf16): row r, k = half*8+j ----
        bf16x8 afrag;
        afrag[0] = f2bf(xa.x); afrag[1] = f2bf(xa.y);
        afrag[2] = f2bf(xa.z); afrag[3] = f2bf(xa.w);
        afrag[4] = f2bf(xb.x); afrag[5] = f2bf(xb.y);
        afrag[6] = f2bf(xb.z); afrag[7] = f2bf(xb.w);

        // h writes visible to whole wave before the c-loop reads
        asm volatile("s_waitcnt lgkmcnt(0)" ::: "memory");

        // ---- T = XE @ W2c per c-tile (MFMA), contract with h on VALU ----
        // D layout (m89-verified): col = l&15 (=o), row = (l>>4)*4 + reg (=edge)
        float s0 = 0.f, s1 = 0.f, s2 = 0.f, s3 = 0.f;
        #pragma unroll
        for (int c = 0; c < 17; ++c) {
            f32x4 t = __builtin_amdgcn_mfma_f32_16x16x32_bf16(
                afrag, bfrag[c], (f32x4){0.f, 0.f, 0.f, 0.f}, 0, 0, 0);
            const float4 h4 = *reinterpret_cast<const float4*>(
                &h_lds[wv][c][half * 4]);
            s0 += h4.x * t[0];
            s1 += h4.y * t[1];
            s2 += h4.z * t[2];
            s3 += h4.w * t[3];
        }

        // ---- epilogue: tanh, norm scale, scatter-add ----
        float sv[4] = {s0, s1, s2, s3};
        #pragma unroll
        for (int q = 0; q < 4; ++q) {
            const int e = e0 + half * 4 + q;
            const float s = sv[q];
            const float t = __expf(-2.0f * fabsf(s));
            float th = (1.0f - t) / (1.0f + t);
            th = copysignf(th, s);
            const float val = th * nrm[e];
            const int dst = ei[N_EDGES + e];
            if (MODE == 0) {
                atomicAdd(out + (size_t)dst * 16 + r, val);
            } else {
                // pair adjacent lanes (cols r, r+1) -> one pk_add_f16 per pair
                const float vpart = __shfl_xor(val, 1);
                if ((r & 1) == 0) {
                    const unsigned short hlo = __half_as_ushort(__float2half(val));
                    const unsigned short hhi = __half_as_ushort(__float2half(vpart));
                    const unsigned int pk = (unsigned int)hlo |
                                            ((unsigned int)hhi << 16);
                    const unsigned long long addr =
                        (unsigned long long)(accum + ((size_t)dst * 16 + r));
                    asm volatile("global_atomic_pk_add_f16 %0, %1, off"
                                 :: "v"(addr), "v"(pk) : "memory");
                }
            }
        }
    }
}

__global__ __launch_bounds__(256)
void convert_f16_to_f32(const __half* __restrict__ accum,
                        float* __restrict__ out, int n)
{
    const int i = blockIdx.x * 256 + threadIdx.x;
    if (i < n) out[i] = __half2float(accum[i]);
}

extern "C" void kernel_launch(void* const* d_in, const int* in_sizes, int n_in,
                              void* d_out, int out_size, void* d_ws, size_t ws_size,
                              hipStream_t stream) {
    const float* x   = (const float*)d_in[0];
    const int*   ei  = (const int*)d_in[1];     // harness delivers ints as int32
    const float* ev  = (const float*)d_in[2];
    const float* nrm = (const float*)d_in[3];
    const float* W1  = (const float*)d_in[4];
    const float* b1  = (const float*)d_in[5];
    const float* W2  = (const float*)d_in[6];
    const float* b2  = (const float*)d_in[7];
    float* out = (float*)d_out;

    const int ngroups = N_EDGES / 16;   // 40000, exact
    dim3 grid(2048), block(256);

    const size_t accum_bytes = (size_t)out_size * sizeof(__half);

    if (ws_size >= accum_bytes) {
        // f16 packed-atomic accumulation path
        __half* accum = (__half*)d_ws;
        hipMemsetAsync(accum, 0, accum_bytes, stream);
        hipLaunchKernelGGL((edge_hyper_kernel<1>), grid, block, 0, stream,
                           x, ei, ev, nrm, W1, b1, W2, b2, out, accum, ngroups);
        hipLaunchKernelGGL(convert_f16_to_f32,
                           dim3((out_size + 255) / 256), block, 0, stream,
                           accum, out, out_size);
    } else {
        // fallback: f32 atomics directly into out
        hipMemsetAsync(out, 0, (size_t)out_size * sizeof(float), stream);
        hipLaunchKernelGGL((edge_hyper_kernel<0>), grid, block, 0, stream,
                           x, ei, ev, nrm, W1, b1, W2, b2, out, (__half*)d_ws,
                           ngroups);
    }
}

// Round 4
// 78.778 us; speedup vs baseline: 2.3647x; 2.3647x over previous
//
#include <hip/hip_runtime.h>
#include <hip/hip_bf16.h>

#define N_NODES 50000
#define N_EDGES 640000

typedef __attribute__((ext_vector_type(8))) short bf16x8;
typedef __attribute__((ext_vector_type(4))) float f32x4;

static __device__ __forceinline__ short f2bf(float f) {
    __hip_bfloat16 h = __float2bfloat16(f);
    return *reinterpret_cast<const short*>(&h);
}

__global__ __launch_bounds__(256)
void edge_hyper_kernel(const float* __restrict__ x,
                       const int* __restrict__ ei,      // int32 [2][E]
                       const float* __restrict__ ev,
                       const float* __restrict__ nrm,
                       const float* __restrict__ W1,
                       const float* __restrict__ b1,
                       const float* __restrict__ W2,
                       const float* __restrict__ b2,
                       float* __restrict__ out,
                       int ngroups)
{
    __shared__ float h_lds[4][17][16];

    const int tid  = threadIdx.x;
    const int wv   = tid >> 6;       // wave in block
    const int l    = tid & 63;       // lane
    const int r    = l & 15;         // A-row edge index in group / output col o
    const int half = l >> 4;         // 0..3

    // ---- B fragments: 17 c-tiles (c=0..15 from W2, c=16 = bias b2) ----
    // Tile c holds B[k=i, n=o] = W2[c, o*32 + i]; lane l: n = l&15,
    // k = (l>>4)*8 + j -> 8 consecutive floats. Same assumed k-map for A
    // and B, so any true k-permutation cancels in the K-sum.
    bf16x8 bfrag[17];
    {
        const int koff = half * 8;
        #pragma unroll
        for (int c = 0; c < 16; ++c) {
            const float* p = W2 + c * 512 + r * 32 + koff;
            bf16x8 t;
            #pragma unroll
            for (int j = 0; j < 8; ++j) t[j] = f2bf(p[j]);
            bfrag[c] = t;
        }
        const float* p = b2 + r * 32 + koff;
        bf16x8 t;
        #pragma unroll
        for (int j = 0; j < 8; ++j) t[j] = f2bf(p[j]);
        bfrag[16] = t;
    }

    // ---- per-lane hypernetwork constants: lane computes h[c] for
    // c = half*4+q, q=0..3, for edge e0+r ----
    float w1v0[4], w1v1[4], w1v2[4], b1v[4];
    #pragma unroll
    for (int q = 0; q < 4; ++q) {
        const int c = half * 4 + q;
        w1v0[q] = W1[c];
        w1v1[q] = W1[16 + c];
        w1v2[q] = W1[32 + c];
        b1v[q]  = b1[c];
    }

    // bias row of the h-contraction is constant 1.0 (folds b2 tile in)
    if (half == 0) h_lds[wv][16][r] = 1.0f;

    const int gw = blockIdx.x * 4 + wv;
    const int nw = gridDim.x * 4;
    if (gw >= ngroups) return;

    // ---- software-pipeline prologue: loads for first group ----
    int g = gw;
    int    idx_c;
    float  v0_c, v1_c, v2_c;
    float4 xa_c, xb_c, nr_c;
    {
        const int e0 = g * 16;
        idx_c = ei[(half >= 2 ? N_EDGES : 0) + e0 + r];
        v0_c  = ev[(e0 + r) * 3 + 0];
        v1_c  = ev[(e0 + r) * 3 + 1];
        v2_c  = ev[(e0 + r) * 3 + 2];
        nr_c  = *reinterpret_cast<const float4*>(nrm + e0 + half * 4);
        const float4* xr = reinterpret_cast<const float4*>(
            x + (size_t)idx_c * 16 + (half & 1) * 8);
        xa_c = xr[0];
        xb_c = xr[1];
    }

    while (g < ngroups) {
        const int e0   = g * 16;
        const int gn   = g + nw;
        const bool hasn = gn < ngroups;

        // ---- issue NEXT group's independent loads first (ei/ev/nrm) ----
        int    idx_n = 0;
        float  v0_n = 0.f, v1_n = 0.f, v2_n = 0.f;
        float4 nr_n = {0.f, 0.f, 0.f, 0.f};
        if (hasn) {
            const int e0n = gn * 16;
            idx_n = ei[(half >= 2 ? N_EDGES : 0) + e0n + r];
            v0_n  = ev[(e0n + r) * 3 + 0];
            v1_n  = ev[(e0n + r) * 3 + 1];
            v2_n  = ev[(e0n + r) * 3 + 2];
            nr_n  = *reinterpret_cast<const float4*>(nrm + e0n + half * 4);
        }

        // ---- hypernetwork h = relu(ev@W1 + b1) for CURRENT group ----
        // drain previous iteration's h reads before overwrite (wave-private)
        asm volatile("s_waitcnt lgkmcnt(0)" ::: "memory");
        #pragma unroll
        for (int q = 0; q < 4; ++q) {
            float hv = b1v[q] + v0_c * w1v0[q] + v1_c * w1v1[q] + v2_c * w1v2[q];
            h_lds[wv][half * 4 + q][r] = fmaxf(hv, 0.0f);
        }

        // ---- A fragment (xe in bf16) from prefetched x ----
        bf16x8 afrag;
        afrag[0] = f2bf(xa_c.x); afrag[1] = f2bf(xa_c.y);
        afrag[2] = f2bf(xa_c.z); afrag[3] = f2bf(xa_c.w);
        afrag[4] = f2bf(xb_c.x); afrag[5] = f2bf(xb_c.y);
        afrag[6] = f2bf(xb_c.z); afrag[7] = f2bf(xb_c.w);

        // ---- issue NEXT group's dependent x gather (hides under MFMA) ----
        float4 xa_n = {0.f,0.f,0.f,0.f}, xb_n = {0.f,0.f,0.f,0.f};
        if (hasn) {
            const float4* xr = reinterpret_cast<const float4*>(
                x + (size_t)idx_n * 16 + (half & 1) * 8);
            xa_n = xr[0];
            xb_n = xr[1];
        }

        // h writes visible to whole wave before the c-loop reads
        asm volatile("s_waitcnt lgkmcnt(0)" ::: "memory");

        // ---- T = XE @ W2c per c-tile (MFMA), contract with h on VALU ----
        // D layout (m89-verified): col = l&15 (=o), row = (l>>4)*4 + reg (=edge)
        float s0 = 0.f, s1 = 0.f, s2 = 0.f, s3 = 0.f;
        #pragma unroll
        for (int c = 0; c < 17; ++c) {
            f32x4 t = __builtin_amdgcn_mfma_f32_16x16x32_bf16(
                afrag, bfrag[c], (f32x4){0.f, 0.f, 0.f, 0.f}, 0, 0, 0);
            const float4 h4 = *reinterpret_cast<const float4*>(
                &h_lds[wv][c][half * 4]);
            s0 += h4.x * t[0];
            s1 += h4.y * t[1];
            s2 += h4.z * t[2];
            s3 += h4.w * t[3];
        }

        // ---- epilogue: tanh, norm scale, scatter-add (f32 atomics) ----
        const float nrv[4] = {nr_c.x, nr_c.y, nr_c.z, nr_c.w};
        const float sv[4]  = {s0, s1, s2, s3};
        #pragma unroll
        for (int q = 0; q < 4; ++q) {
            const int e = e0 + half * 4 + q;
            const float s = sv[q];
            const float t = __expf(-2.0f * fabsf(s));
            float th = (1.0f - t) / (1.0f + t);
            th = copysignf(th, s);
            const float val = th * nrv[q];
            const int dst = ei[N_EDGES + e];
            atomicAdd(out + (size_t)dst * 16 + r, val);
        }

        // ---- rotate pipeline state ----
        idx_c = idx_n;
        v0_c = v0_n; v1_c = v1_n; v2_c = v2_n;
        nr_c = nr_n;
        xa_c = xa_n; xb_c = xb_n;
        g = gn;
    }
}

extern "C" void kernel_launch(void* const* d_in, const int* in_sizes, int n_in,
                              void* d_out, int out_size, void* d_ws, size_t ws_size,
                              hipStream_t stream) {
    const float* x   = (const float*)d_in[0];
    const int*   ei  = (const int*)d_in[1];     // harness delivers ints as int32
    const float* ev  = (const float*)d_in[2];
    const float* nrm = (const float*)d_in[3];
    const float* W1  = (const float*)d_in[4];
    const float* b1  = (const float*)d_in[5];
    const float* W2  = (const float*)d_in[6];
    const float* b2  = (const float*)d_in[7];
    float* out = (float*)d_out;

    hipMemsetAsync(out, 0, (size_t)out_size * sizeof(float), stream);

    const int ngroups = N_EDGES / 16;   // 40000, exact
    dim3 grid(2048), block(256);
    hipLaunchKernelGGL(edge_hyper_kernel, grid, block, 0, stream,
                       x, ei, ev, nrm, W1, b1, W2, b2, out, ngroups);
}